// Round 10
// baseline (848.953 us; speedup 1.0000x reference)
//
#include <hip/hip_runtime.h>

typedef __attribute__((ext_vector_type(8))) short short8;
typedef __attribute__((ext_vector_type(4))) float f32x4;
typedef __attribute__((ext_vector_type(4))) int int4v;
typedef unsigned short ushort_t;
typedef unsigned char u8;

#define E 512
#define SS 16
#define BB 128
#define IND 256
#define OUTD 128
#define MEMD 32769
#define NEGV -1000000000.0f
#define EPSV 1e-5f

#define MFMA  __builtin_amdgcn_mfma_f32_16x16x32_bf16
#define MFMAI8(a, b, c) __builtin_amdgcn_mfma_i32_16x16x64_i8((a), (b), (c), 0, 0, 0)

// forced-issue 16B load, saddr form: base block-uniform (SGPR pair),
// thread-dependent terms in the per-lane VGPR offset.
#define GLV(dst, base, off) \
  asm volatile("global_load_dwordx4 %0, %1, %2" : "=v"(dst) : "v"(off), "s"(base))
// wait tied to consumed register
#define WVX_(x, n) asm volatile("s_waitcnt vmcnt(" #n ")" : "+v"(x))
#define WVX(x, n) WVX_(x, n)

// LDS-only barrier: does not drain vmcnt
__device__ __forceinline__ void bar_lds() {
  asm volatile("s_waitcnt lgkmcnt(0)\ns_barrier" ::: "memory");
}

__device__ __forceinline__ unsigned short f2bf(float f) {
  union { float f; unsigned int u; } v; v.f = f;
  unsigned int u = v.u;
  unsigned int r = u + 0x7fffu + ((u >> 16) & 1u);
  return (unsigned short)(r >> 16);
}
__device__ __forceinline__ float bf2f(unsigned short h) {
  union { unsigned int u; float f; } v; v.u = ((unsigned int)h) << 16;
  return v.f;
}
__device__ __forceinline__ int q8(float x) {  // round-to-nearest int8 with clamp
  return __float2int_rn(fminf(fmaxf(x, -127.f), 127.f));
}
// quantize 8 fp32 (scale 32) -> 8 int8 packed into two dwords at dst
__device__ __forceinline__ void quant8_store(u8* dst, const float* h) {
  int q[8];
#pragma unroll
  for (int j = 0; j < 8; ++j) q[j] = q8(h[j] * 32.f);
  unsigned int p0 = (q[0]&255) | ((q[1]&255)<<8) | ((q[2]&255)<<16) | ((q[3]&255)<<24);
  unsigned int p1 = (q[4]&255) | ((q[5]&255)<<8) | ((q[6]&255)<<16) | ((q[7]&255)<<24);
  *(unsigned int*)(dst)     = p0;
  *(unsigned int*)(dst + 4) = p1;
}

// ---------------- K0a: per-row weight scales (wave-per-row, coalesced) ----------------
// rows: [0,3072)=ipw(2x1536), [3072,4096)=aow(2x512), [4096,5120)=ffw(2x512), [5120,5248)=wout(128)
__global__ __launch_bounds__(256) void wscale_kernel(
    const float* __restrict__ ipw, const float* __restrict__ aow,
    const float* __restrict__ ffw, const float* __restrict__ wout,
    float* __restrict__ scl)
{
  int wv = blockIdx.x * 4 + (threadIdx.x >> 6);   // grid 1312*4 = 5248 rows exactly
  int lane = threadIdx.x & 63;
  const float* row;
  if (wv < 3072)      row = ipw  + (size_t)wv * 512;
  else if (wv < 4096) row = aow  + (size_t)(wv - 3072) * 512;
  else if (wv < 5120) row = ffw  + (size_t)(wv - 4096) * 512;
  else                row = wout + (size_t)(wv - 5120) * 512;
  float m = 0.f;
#pragma unroll
  for (int k = 0; k < 8; ++k) m = fmaxf(m, fabsf(row[lane + 64*k]));
  m = fmaxf(m, __shfl_xor(m, 1));
  m = fmaxf(m, __shfl_xor(m, 2));
  m = fmaxf(m, __shfl_xor(m, 4));
  m = fmaxf(m, __shfl_xor(m, 8));
  m = fmaxf(m, __shfl_xor(m, 16));
  m = fmaxf(m, __shfl_xor(m, 32));
  if (lane == 0) scl[wv] = (m > 0.f) ? m * (1.f / 127.f) : 1.f;
}

// ---------------- K0b: pack weights to int8 MFMA tiles ----------------
// dst[((T*8+kt)*64+lane)*16 + j] = i8(W[T*16+(lane&15)][kt*64+(lane>>4)*16+j] / scl_row)
__device__ __forceinline__ void packmatI8(u8* __restrict__ dst, const float* __restrict__ src,
                                          const float* __restrict__ sclrow,
                                          int n, int tid, int stride) {
  for (int i = tid; i < n; i += stride) {
    int j = i & 15, lane = (i >> 4) & 63, kt = (i >> 10) & 7, T = i >> 13;
    int row = T * 16 + (lane & 15);
    int col = kt * 64 + ((lane >> 4) << 4) + j;
    float s = sclrow[row];
    int q = q8(src[(size_t)row * 512 + col] / s);
    dst[i] = (u8)(q & 0xff);
  }
}

__global__ __launch_bounds__(256) void wconvert_kernel(
    const float* __restrict__ ipw, const float* __restrict__ aow,
    const float* __restrict__ ffw, const float* __restrict__ wout,
    const float* __restrict__ win, const float* __restrict__ scl,
    u8* __restrict__ win8, u8* __restrict__ wo8,
    u8* __restrict__ wf8, u8* __restrict__ wout8,
    float* __restrict__ winT)
{
  const int tid = blockIdx.x * blockDim.x + threadIdx.x;
  const int stride = gridDim.x * blockDim.x;
  packmatI8(win8,  ipw,  scl,        2*1536*E, tid, stride);
  packmatI8(wo8,   aow,  scl + 3072, 2*E*E,    tid, stride);
  packmatI8(wf8,   ffw,  scl + 4096, 2*E*E,    tid, stride);
  packmatI8(wout8, wout, scl + 5120, OUTD*E,   tid, stride);
  for (int i = tid; i < E*IND; i += stride) {
    int o = i / IND, k = i % IND;
    winT[k*E + o] = win[i];
  }
}

// ---------------- K1: X = seq @ Win^T + b_in ----------------
__global__ __launch_bounds__(512) void xproj_kernel(
    const float* __restrict__ seq, const float* __restrict__ winT,
    const float* __restrict__ b_in, float* __restrict__ X)
{
  const int b = blockIdx.x;
  const int th = threadIdx.x;
  __shared__ float sq[SS * IND];
  for (int i = th; i < SS * IND; i += 512) {
    int t = i >> 8, k = i & 255;
    sq[i] = seq[((size_t)t * BB + b) * IND + k];
  }
  __syncthreads();
  float acc[SS];
#pragma unroll
  for (int t = 0; t < SS; ++t) acc[t] = 0.f;
  for (int k = 0; k < IND; ++k) {
    float w = winT[k * E + th];
#pragma unroll
    for (int t = 0; t < SS; ++t) acc[t] += sq[t * IND + k] * w;
  }
  float bias = b_in[th];
#pragma unroll
  for (int t = 0; t < SS; ++t)
    X[((size_t)t * BB + b) * E + th] = acc[t] + bias;
}

// ---------------- K2: main recurrent encoder ----------------
// amdgpu_waves_per_eu(4,4): LDS (~95.5 KB) limits us to 1 block/CU = 4
// waves/EU anyway; without the max=4 the allocator targets 8 waves/EU,
// pins VGPR=64, and spills ~24 regs/wave to scratch (R6/R9: +300 MB HBM).
__global__ __launch_bounds__(1024, 4) __attribute__((amdgpu_waves_per_eu(4, 4)))
void encoder_kernel(
    const float* __restrict__ Xpre, const float* __restrict__ hstate,
    const u8* __restrict__ win8, const u8* __restrict__ wo8,
    const u8* __restrict__ wf8, const u8* __restrict__ wout8,
    const float* __restrict__ scl,
    const float* __restrict__ ipb, const float* __restrict__ aob,
    const float* __restrict__ l1s, const float* __restrict__ l1b,
    const float* __restrict__ l2s, const float* __restrict__ l2b,
    const float* __restrict__ ffb, const float* __restrict__ bout,
    float* __restrict__ out)
{
  const int b = blockIdx.x;
  const int th = threadIdx.x;
  const int lane = th & 63;
  const int w = th >> 6;         // wave 0..15
  const int g = lane >> 4;       // quad
  const int c = lane & 15;       // lane-in-quad
  const int fb = lane << 3;      // 8-feature chunk for LN
  const int fq = w*16 + c;       // per-lane output-feature index within a 256-block

  // per-lane byte offsets for packed-weight loads (tile w + lane + chunk)
  unsigned int vofs[8];
#pragma unroll
  for (int i = 0; i < 8; ++i)
    vofs[i] = (unsigned int)w * 8192u + (unsigned int)lane * 16u + (unsigned int)i * 1024u;

  // LDS ~95.5 KB
  __shared__ u8 h_i8[16*528];         // h int8 (x32), stride 528 (16B aligned)
  __shared__ ushort_t qk[9216];       // q[4][16][72], k[4][16][72]; dbuf alias
  __shared__ ushort_t vbuf[10240];    // vT[4][64][40] bf16 (token pads zeroed once)
  __shared__ ushort_t p_lds[2560];    // P[4][16][40] bf16 (pad cols zeroed once)
  __shared__ u8 abuf_i8[16*272];      // attn int8 (x32) -- dedicated (no qk alias)
  __shared__ ushort_t lnp[4096];      // [l][{l1s,l1b,l2s,l2b}][512] bf16
  __shared__ float x_lds[SS*E];       // X for this b, all 16 timesteps (fp32)

  ushort_t* q_lds = qk;
  ushort_t* k_lds = qk + 4608;
  ushort_t* dbuf = qk;                // [16][520] bf16

  const size_t hsb = (size_t)b * MEMD;
  const int ci0 = (int)hstate[hsb + 32768];
  const float boutr = bout[(w&7)*16 + c];
  const float mw = scl[5120 + (w&7)*16 + c] * (1.f/32.f);

  float hreg[8];
  {
#pragma unroll
    for (int j = 0; j < 8; ++j) hreg[j] = hstate[hsb + (size_t)w*E + fb + j];
    quant8_store(h_i8 + w*528 + fb, hreg);
  }
  // t=0 insert directly from global (own-wave loads, before the prologue barrier)
  if (ci0 < 16 && w == ci0) {
#pragma unroll
    for (int j = 0; j < 8; ++j) hreg[j] = Xpre[(size_t)b*E + fb + j];
    quant8_store(h_i8 + w*528 + fb, hreg);
  }
  // stage all 16 timesteps of X into LDS (coalesced; read-only afterwards)
  for (int i = th; i < SS*E; i += 1024) {
    int tt = i >> 9, e = i & 511;
    x_lds[i] = Xpre[((size_t)tt*BB + b)*E + e];
  }
  for (int i = th; i < 2560; i += 1024) p_lds[i] = 0;
  for (int i = th; i < 4096; i += 1024) {
    int h2 = i >> 10, dh = (i >> 4) & 63, t16 = i & 15;
    vbuf[h2*2560 + dh*40 + 16 + t16] = 0;
  }
  for (int i = th; i < 4096; i += 1024) {
    int l = i >> 11, arr = (i >> 9) & 3, idx = i & 511;
    float v = (arr == 0 ? l1s : arr == 1 ? l1b : arr == 2 ? l2s : l2b)[l*512 + idx];
    lnp[i] = f2bf(v);
  }
  bar_lds();

#pragma unroll 1
  for (int t = 0; t < SS; ++t) {
    const int cic = ci0 + t;
    // (x_t already inserted: t=0 in prologue, t>0 at previous WOUT tail)

#pragma unroll 1
    for (int l = 0; l < 2; ++l) {
      // per-layer biases + dequant multipliers -> registers (nothing in flight here)
      const float* bq_ = ipb + l*1536 + fq;
      const float biq0 = bq_[0],    biq1 = bq_[256];
      const float bik0 = bq_[512],  bik1 = bq_[768];
      const float biv0 = bq_[1024], biv1 = bq_[1280];
      const float aob0 = aob[l*512 + fq], aob1 = aob[l*512 + 256 + fq];
      const float ffb0 = ffb[l*512 + fq], ffb1 = ffb[l*512 + 256 + fq];
      const float* sip = scl + l*1536;
      const float mq0 = sip[fq]       * (1.f/32.f), mq1 = sip[256 + fq]  * (1.f/32.f);
      const float mk0 = sip[512 + fq] * (1.f/32.f), mk1 = sip[768 + fq]  * (1.f/32.f);
      const float mv0 = sip[1024+ fq] * (1.f/32.f), mv1 = sip[1280 + fq] * (1.f/32.f);
      const float* swo = scl + 3072 + l*512;
      const float mo0 = swo[fq] * (1.f/32.f), mo1 = swo[256 + fq] * (1.f/32.f);
      const float* swf = scl + 4096 + l*512;
      const float mf0 = swf[fq] * (1.f/32.f), mf1 = swf[256 + fq] * (1.f/32.f);

      const u8* wiL = win8 + (size_t)l*786432;
      const u8* woL = wo8 + (size_t)l*262144;
      const u8* wfL = wf8 + (size_t)l*262144;

      int4v oacc0 = {0,0,0,0}, oacc1 = oacc0;
      // QKV weight ring, hoisted to layer scope: pass1's chunks 0,1 are
      // prefetched at OP(p0) tail (no barrier crossing; uniform branch).
      int4v Bq[4], Bk[4], Bv[4];

#pragma unroll 1
      for (int pass = 0; pass < 2; ++pass) {
        const int hl = w >> 2;
        const int dhb = (w & 3) * 16;

        // ---- QKV GEMM (i8): K=512, 8 chunks x 3 streams, depth-4 pipeline ----
        {
          const u8* A8 = h_i8 + c*528 + g*16;
          const u8* uq = wiL + (size_t)pass*131072;  // block-uniform bases
          const u8* uk = uq + 262144;
          const u8* uv = uq + 524288;
          int4v aq = {0,0,0,0}, ak = aq, av = aq;
          // chunks 0,1: issued here for pass0; already in flight for pass1
          if (pass == 0) {
            GLV(Bq[0], uq, vofs[0]); GLV(Bk[0], uk, vofs[0]); GLV(Bv[0], uv, vofs[0]);
            GLV(Bq[1], uq, vofs[1]); GLV(Bk[1], uk, vofs[1]); GLV(Bv[1], uv, vofs[1]);
          }
          GLV(Bq[2], uq, vofs[2]); GLV(Bk[2], uk, vofs[2]); GLV(Bv[2], uv, vofs[2]);
          GLV(Bq[3], uq, vofs[3]); GLV(Bk[3], uk, vofs[3]); GLV(Bv[3], uv, vofs[3]);

#define QKV_STEP(kt2, nq, nk, nv) { \
            int4v a = *(const int4v*)(A8 + (kt2)*64); \
            WVX(Bq[(kt2)&3], nq); aq = MFMAI8(a, Bq[(kt2)&3], aq); \
            WVX(Bk[(kt2)&3], nk); ak = MFMAI8(a, Bk[(kt2)&3], ak); \
            WVX(Bv[(kt2)&3], nv); av = MFMAI8(a, Bv[(kt2)&3], av); \
            if ((kt2) < 4) { \
              GLV(Bq[(kt2)&3], uq, vofs[(kt2)+4]); \
              GLV(Bk[(kt2)&3], uk, vofs[(kt2)+4]); \
              GLV(Bv[(kt2)&3], uv, vofs[(kt2)+4]); \
            } }
          QKV_STEP(0, 11, 10, 9)
          QKV_STEP(1, 11, 10, 9)
          QKV_STEP(2, 11, 10, 9)
          QKV_STEP(3, 11, 10, 9)
          QKV_STEP(4, 11, 10, 9)
          QKV_STEP(5,  8,  7, 6)
          QKV_STEP(6,  5,  4, 3)
          QKV_STEP(7,  2,  1, 0)

          const float biq = pass ? biq1 : biq0;
          const float bik = pass ? bik1 : bik0;
          const float biv = pass ? biv1 : biv0;
          const float mq = pass ? mq1 : mq0;
          const float mk = pass ? mk1 : mk0;
          const float mv = pass ? mv1 : mv0;
#pragma unroll
          for (int r = 0; r < 4; ++r) {
            int tok = 4*g + r;
            q_lds[hl*1152 + tok*72 + dhb + c] = f2bf((float)aq[r]*mq + biq);
            k_lds[hl*1152 + tok*72 + dhb + c] = f2bf((float)ak[r]*mk + bik);
            vbuf[hl*2560 + (dhb + c)*40 + tok] = f2bf((float)av[r]*mv + biv);
          }
        }
        bar_lds();

        // ---- out-proj weights (i8): 8 loads, in flight through softmax+PV ----
        int4v O0[4], O1[4];
        {
          const u8* uo0 = woL + pass*4096;      // uniform (chunks pass*4..pass*4+3)
          const u8* uo1 = uo0 + 131072;         // tile w+16
          GLV(O0[0], uo0, vofs[0]); GLV(O1[0], uo1, vofs[0]);
          GLV(O0[1], uo0, vofs[1]); GLV(O1[1], uo1, vofs[1]);
          GLV(O0[2], uo0, vofs[2]); GLV(O1[2], uo1, vofs[2]);
          GLV(O0[3], uo0, vofs[3]); GLV(O1[3], uo1, vofs[3]);
        }

        // ---- scores + masked softmax (bf16): waves 0..3 ----
        if (w < 4) {
          f32x4 sc = {0.f,0.f,0.f,0.f};
#pragma unroll
          for (int k2 = 0; k2 < 2; ++k2) {
            short8 qa = *(const short8*)&q_lds[w*1152 + c*72 + k2*32 + g*8];
            short8 kb = *(const short8*)&k_lds[w*1152 + c*72 + k2*32 + g*8];
            sc = MFMA(qa, kb, sc, 0,0,0);
          }
          float sv[4], mx[4], ex[4], sm[4];
#pragma unroll
          for (int r = 0; r < 4; ++r) {
            int row = 4*g + r;
            bool msk = ((c > cic) || (row > cic)) && (c != 0);
            sv[r] = msk ? NEGV : sc[r]*0.125f;
            mx[r] = sv[r];
          }
#pragma unroll
          for (int r = 0; r < 4; ++r) {
            mx[r] = fmaxf(mx[r], __shfl_xor(mx[r], 1));
            mx[r] = fmaxf(mx[r], __shfl_xor(mx[r], 2));
            mx[r] = fmaxf(mx[r], __shfl_xor(mx[r], 4));
            mx[r] = fmaxf(mx[r], __shfl_xor(mx[r], 8));
          }
#pragma unroll
          for (int r = 0; r < 4; ++r) { ex[r] = __expf(sv[r] - mx[r]); sm[r] = ex[r]; }
#pragma unroll
          for (int r = 0; r < 4; ++r) {
            sm[r] += __shfl_xor(sm[r], 1);
            sm[r] += __shfl_xor(sm[r], 2);
            sm[r] += __shfl_xor(sm[r], 4);
            sm[r] += __shfl_xor(sm[r], 8);
          }
#pragma unroll
          for (int r = 0; r < 4; ++r)
            p_lds[w*640 + (4*g + r)*40 + c] = f2bf(ex[r] / sm[r]);
        }
        bar_lds();

        // ---- PV (bf16) -> abuf int8 (x32), dedicated buffer ----
        {
          const int hl2 = w >> 2, ct = w & 3;
          short8 pa = *(const short8*)&p_lds[hl2*640 + c*40 + g*8];
          short8 vb = *(const short8*)&vbuf[hl2*2560 + (ct*16 + c)*40 + g*8];
          f32x4 ov = {0.f,0.f,0.f,0.f};
          ov = MFMA(pa, vb, ov, 0,0,0);
#pragma unroll
          for (int r = 0; r < 4; ++r)
            abuf_i8[(4*g + r)*272 + hl2*64 + ct*16 + c] = (u8)(q8(ov[r]*32.f) & 0xff);
        }
        bar_lds();

        // ---- out-proj partial (i8), K=256 ----
        // no trailing barrier: QKV pass1 writes (q/k/vbuf) conflict only with
        // SM/PV pass0 reads, which are >=2 barriers upstream; abuf is dedicated.
        {
          const u8* A8o = abuf_i8 + c*272 + g*16;
#define OP_STEP(kt2, n0, n1) { \
            int4v a = *(const int4v*)(A8o + (kt2)*64); \
            WVX(O0[kt2], n0); oacc0 = MFMAI8(a, O0[kt2], oacc0); \
            WVX(O1[kt2], n1); oacc1 = MFMAI8(a, O1[kt2], oacc1); }
          OP_STEP(0, 7, 6)
          OP_STEP(1, 5, 4)
          OP_STEP(2, 3, 2)
          OP_STEP(3, 1, 0)
          // prefetch pass1's QKV chunks 0,1 (outstanding is 0 here; order
          // q,k,v per chunk matches the QKV-head order, so counts hold)
          if (pass == 0) {
            const u8* nq = wiL + 131072;
            const u8* nk = nq + 262144;
            const u8* nv = nq + 524288;
            GLV(Bq[0], nq, vofs[0]); GLV(Bk[0], nk, vofs[0]); GLV(Bv[0], nv, vofs[0]);
            GLV(Bq[1], nq, vofs[1]); GLV(Bk[1], nk, vofs[1]); GLV(Bv[1], nv, vofs[1]);
          }
        }
      } // pass

      // ---- write out-proj result (dequant + attn-out bias) ----
      // dbuf overlaps q/k_lds; last readers (SM pass1) are 2 barriers upstream.
#pragma unroll
      for (int r = 0; r < 4; ++r) {
        dbuf[(4*g + r)*520 + fq]       = f2bf((float)oacc0[r]*mo0 + aob0);
        dbuf[(4*g + r)*520 + 256 + fq] = f2bf((float)oacc1[r]*mo1 + aob1);
      }
      bar_lds();

      // ---- FF weight prologue (i8, 8 loads), hides behind LN1 ----
      int4v F0[4], F1[4];
      const u8* uf0 = wfL;
      const u8* uf1 = wfL + 131072;
      GLV(F0[0], uf0, vofs[0]); GLV(F1[0], uf1, vofs[0]);
      GLV(F0[1], uf0, vofs[1]); GLV(F1[1], uf1, vofs[1]);
      GLV(F0[2], uf0, vofs[2]); GLV(F1[2], uf1, vofs[2]);
      GLV(F0[3], uf0, vofs[3]); GLV(F1[3], uf1, vofs[3]);

      // ---- residual + LN1 (params from LDS) ----
      {
        const ushort_t* lpS = lnp + l*2048;
        const ushort_t* lpB = lnp + l*2048 + 512;
        float sum = 0.f;
#pragma unroll
        for (int j = 0; j < 8; ++j) {
          hreg[j] += bf2f(dbuf[w*520 + fb + j]);
          sum += hreg[j];
        }
        sum += __shfl_xor(sum, 1); sum += __shfl_xor(sum, 2); sum += __shfl_xor(sum, 4);
        sum += __shfl_xor(sum, 8); sum += __shfl_xor(sum, 16); sum += __shfl_xor(sum, 32);
        float mu = sum * (1.0f/512.0f);
        float s2 = 0.f;
#pragma unroll
        for (int j = 0; j < 8; ++j) { float dd = hreg[j] - mu; s2 += dd*dd; }
        s2 += __shfl_xor(s2, 1); s2 += __shfl_xor(s2, 2); s2 += __shfl_xor(s2, 4);
        s2 += __shfl_xor(s2, 8); s2 += __shfl_xor(s2, 16); s2 += __shfl_xor(s2, 32);
        float rs = rsqrtf(s2 * (1.0f/512.0f) + EPSV);
#pragma unroll
        for (int j = 0; j < 8; ++j)
          hreg[j] = (hreg[j] - mu) * rs * bf2f(lpS[fb + j]) + bf2f(lpB[fb + j]);
        quant8_store(h_i8 + w*528 + fb, hreg);
      }
      bar_lds();

      // ---- FF GEMM (i8): K=512, forced pipeline ----
      {
        int4v f0 = {0,0,0,0}, f1 = f0;
        const u8* A8 = h_i8 + c*528 + g*16;
#define FF_STEP(kt2, n0, n1) { \
          int4v a = *(const int4v*)(A8 + (kt2)*64); \
          WVX(F0[(kt2)&3], n0); f0 = MFMAI8(a, F0[(kt2)&3], f0); \
          WVX(F1[(kt2)&3], n1); f1 = MFMAI8(a, F1[(kt2)&3], f1); \
          if ((kt2) < 4) { \
            GLV(F0[(kt2)&3], uf0, vofs[(kt2)+4]); \
            GLV(F1[(kt2)&3], uf1, vofs[(kt2)+4]); \
          } }
        FF_STEP(0, 7, 6)
        FF_STEP(1, 7, 6)
        FF_STEP(2, 7, 6)
        FF_STEP(3, 7, 6)
        FF_STEP(4, 7, 6)
        FF_STEP(5, 5, 4)
        FF_STEP(6, 3, 2)
        FF_STEP(7, 1, 0)
        // no barrier here: nothing reads the dbuf region during FF (LN1's
        // reads are behind the LN1-end barrier), and these writes don't
        // touch h_i8 which other waves may still be reading.
#pragma unroll
        for (int r = 0; r < 4; ++r) {
          dbuf[(4*g + r)*520 + fq]       = f2bf((float)f0[r]*mf0 + ffb0);
          dbuf[(4*g + r)*520 + 256 + fq] = f2bf((float)f1[r]*mf1 + ffb1);
        }
      }
      bar_lds();

      // ---- residual + LN2 ----
      {
        const ushort_t* lpS = lnp + l*2048 + 1024;
        const ushort_t* lpB = lnp + l*2048 + 1536;
        float sum = 0.f;
#pragma unroll
        for (int j = 0; j < 8; ++j) {
          hreg[j] += bf2f(dbuf[w*520 + fb + j]);
          sum += hreg[j];
        }
        sum += __shfl_xor(sum, 1); sum += __shfl_xor(sum, 2); sum += __shfl_xor(sum, 4);
        sum += __shfl_xor(sum, 8); sum += __shfl_xor(sum, 16); sum += __shfl_xor(sum, 32);
        float mu = sum * (1.0f/512.0f);
        float s2 = 0.f;
#pragma unroll
        for (int j = 0; j < 8; ++j) { float dd = hreg[j] - mu; s2 += dd*dd; }
        s2 += __shfl_xor(s2, 1); s2 += __shfl_xor(s2, 2); s2 += __shfl_xor(s2, 4);
        s2 += __shfl_xor(s2, 8); s2 += __shfl_xor(s2, 16); s2 += __shfl_xor(s2, 32);
        float rs = rsqrtf(s2 * (1.0f/512.0f) + EPSV);
#pragma unroll
        for (int j = 0; j < 8; ++j)
          hreg[j] = (hreg[j] - mu) * rs * bf2f(lpS[fb + j]) + bf2f(lpB[fb + j]);
        quant8_store(h_i8 + w*528 + fb, hreg);
      }
      bar_lds();
    } // layer

    // ---- output projection (i8): out_t = h[cic] @ Wout^T + b_out ----
    if (w < 8) {
      const int crow = (cic < 15) ? cic : 15;
      const u8* A8 = h_i8 + c*528 + g*16;
      int4v WB[8];
      GLV(WB[0], wout8, vofs[0]); GLV(WB[1], wout8, vofs[1]);
      GLV(WB[2], wout8, vofs[2]); GLV(WB[3], wout8, vofs[3]);
      GLV(WB[4], wout8, vofs[4]); GLV(WB[5], wout8, vofs[5]);
      GLV(WB[6], wout8, vofs[6]); GLV(WB[7], wout8, vofs[7]);
      int4v oo = {0,0,0,0};
#define WOUT_STEP(kt2, n) { \
        int4v a = *(const int4v*)(A8 + (kt2)*64); \
        WVX(WB[kt2], n); oo = MFMAI8(a, WB[kt2], oo); }
      WOUT_STEP(0, 7)
      WOUT_STEP(1, 6)
      WOUT_STEP(2, 5)
      WOUT_STEP(3, 4)
      WOUT_STEP(4, 3)
      WOUT_STEP(5, 2)
      WOUT_STEP(6, 1)
      WOUT_STEP(7, 0)
      if (g == (crow >> 2)) {
        int r = crow & 3;
        int val = (r == 0) ? oo[0] : (r == 1) ? oo[1] : (r == 2) ? oo[2] : oo[3];
        out[((size_t)t*BB + b)*OUTD + w*16 + c] = (float)val * mw + boutr;
      }
    }
    // ---- insert x_{t+1} from LDS during WOUT (racing row cic+1 is never
    // the stored row crow=cic, so its contribution to WOUT is discarded) ----
    {
      const int nx = cic + 1;
      if (nx < 16 && w == nx) {
#pragma unroll
        for (int j = 0; j < 8; ++j) hreg[j] = x_lds[(t+1)*E + fb + j];
        quant8_store(h_i8 + w*528 + fb, hreg);
      }
    }
    bar_lds();
  } // t

  // ---- epilogue: new_h = [h_fin, pad, ci+16] ----
  const size_t OB = (size_t)SS * BB * OUTD;
#pragma unroll
  for (int j = 0; j < 8; ++j)
    out[OB + hsb + (size_t)w*E + fb + j] = hreg[j];
  for (int i = th; i < 48*512; i += 1024)
    out[OB + hsb + 8192 + i] = hstate[hsb + 8192 + i];
  if (th == 0) out[OB + hsb + 32768] = (float)(ci0 + SS);
}

// ---------------- launcher ----------------
extern "C" void kernel_launch(void* const* d_in, const int* in_sizes, int n_in,
                              void* d_out, int out_size, void* d_ws, size_t ws_size,
                              hipStream_t stream) {
  const float* seq  = (const float*)d_in[0];
  const float* hs   = (const float*)d_in[1];
  const float* Win  = (const float*)d_in[2];
  const float* b_in = (const float*)d_in[3];
  const float* Wout = (const float*)d_in[4];
  const float* bo   = (const float*)d_in[5];
  const float* ipw  = (const float*)d_in[6];
  const float* ipb  = (const float*)d_in[7];
  const float* aow  = (const float*)d_in[8];
  const float* aob  = (const float*)d_in[9];
  const float* l1s  = (const float*)d_in[10];
  const float* l1b  = (const float*)d_in[11];
  const float* l2s  = (const float*)d_in[12];
  const float* l2b  = (const float*)d_in[13];
  const float* ffw  = (const float*)d_in[14];
  const float* ffb  = (const float*)d_in[15];

  char* ws = (char*)d_ws;
  u8*    win8  = (u8*)   (ws + 0);          // 1,572,864 B
  u8*    wo8   = (u8*)   (ws + 1572864);    //   524,288 B
  u8*    wf8   = (u8*)   (ws + 2097152);    //   524,288 B
  u8*    wout8 = (u8*)   (ws + 2621440);    //    65,536 B
  float* scl   = (float*)(ws + 2686976);    //    20,992 B (5248 f32)
  float* winT  = (float*)(ws + 2707968);    //   524,288 B
  float* X     = (float*)(ws + 3232256);    // 4,194,304 B

  wscale_kernel<<<1312, 256, 0, stream>>>(ipw, aow, ffw, Wout, scl);
  wconvert_kernel<<<512, 256, 0, stream>>>(ipw, aow, ffw, Wout, Win, scl,
                                           win8, wo8, wf8, wout8, winT);
  xproj_kernel<<<BB, 512, 0, stream>>>(seq, winT, b_in, X);
  encoder_kernel<<<BB, 1024, 0, stream>>>(X, hs, win8, wo8, wf8, wout8, scl,
                                          ipb, aob, l1s, l1b, l2s, l2b, ffb, bo,
                                          (float*)d_out);
}

// Round 11
// 801.143 us; speedup vs baseline: 1.0597x; 1.0597x over previous
//
#include <hip/hip_runtime.h>

typedef __attribute__((ext_vector_type(8))) short short8;
typedef __attribute__((ext_vector_type(4))) float f32x4;
typedef __attribute__((ext_vector_type(4))) int int4v;
typedef unsigned short ushort_t;
typedef unsigned char u8;

#define E 512
#define SS 16
#define BB 128
#define IND 256
#define OUTD 128
#define MEMD 32769
#define NEGV -1000000000.0f
#define EPSV 1e-5f

#define MFMA  __builtin_amdgcn_mfma_f32_16x16x32_bf16
#define MFMAI8(a, b, c) __builtin_amdgcn_mfma_i32_16x16x64_i8((a), (b), (c), 0, 0, 0)

// forced-issue 16B load, saddr form: base block-uniform (SGPR pair),
// thread-dependent terms in the per-lane VGPR offset.
#define GLV(dst, base, off) \
  asm volatile("global_load_dwordx4 %0, %1, %2" : "=v"(dst) : "v"(off), "s"(base))
// wait tied to consumed register
#define WVX_(x, n) asm volatile("s_waitcnt vmcnt(" #n ")" : "+v"(x))
#define WVX(x, n) WVX_(x, n)

// LDS-only barrier: does not drain vmcnt
__device__ __forceinline__ void bar_lds() {
  asm volatile("s_waitcnt lgkmcnt(0)\ns_barrier" ::: "memory");
}

__device__ __forceinline__ unsigned short f2bf(float f) {
  union { float f; unsigned int u; } v; v.f = f;
  unsigned int u = v.u;
  unsigned int r = u + 0x7fffu + ((u >> 16) & 1u);
  return (unsigned short)(r >> 16);
}
__device__ __forceinline__ float bf2f(unsigned short h) {
  union { unsigned int u; float f; } v; v.u = ((unsigned int)h) << 16;
  return v.f;
}
__device__ __forceinline__ int q8(float x) {  // round-to-nearest int8 with clamp
  return __float2int_rn(fminf(fmaxf(x, -127.f), 127.f));
}
// quantize 8 fp32 (scale 32) -> 8 int8 packed into two dwords at dst
__device__ __forceinline__ void quant8_store(u8* dst, const float* h) {
  int q[8];
#pragma unroll
  for (int j = 0; j < 8; ++j) q[j] = q8(h[j] * 32.f);
  unsigned int p0 = (q[0]&255) | ((q[1]&255)<<8) | ((q[2]&255)<<16) | ((q[3]&255)<<24);
  unsigned int p1 = (q[4]&255) | ((q[5]&255)<<8) | ((q[6]&255)<<16) | ((q[7]&255)<<24);
  *(unsigned int*)(dst)     = p0;
  *(unsigned int*)(dst + 4) = p1;
}

// ---------------- K0a: per-row weight scales (wave-per-row, coalesced) ----------------
// rows: [0,3072)=ipw(2x1536), [3072,4096)=aow(2x512), [4096,5120)=ffw(2x512), [5120,5248)=wout(128)
__global__ __launch_bounds__(256) void wscale_kernel(
    const float* __restrict__ ipw, const float* __restrict__ aow,
    const float* __restrict__ ffw, const float* __restrict__ wout,
    float* __restrict__ scl)
{
  int wv = blockIdx.x * 4 + (threadIdx.x >> 6);   // grid 1312*4 = 5248 rows exactly
  int lane = threadIdx.x & 63;
  const float* row;
  if (wv < 3072)      row = ipw  + (size_t)wv * 512;
  else if (wv < 4096) row = aow  + (size_t)(wv - 3072) * 512;
  else if (wv < 5120) row = ffw  + (size_t)(wv - 4096) * 512;
  else                row = wout + (size_t)(wv - 5120) * 512;
  float m = 0.f;
#pragma unroll
  for (int k = 0; k < 8; ++k) m = fmaxf(m, fabsf(row[lane + 64*k]));
  m = fmaxf(m, __shfl_xor(m, 1));
  m = fmaxf(m, __shfl_xor(m, 2));
  m = fmaxf(m, __shfl_xor(m, 4));
  m = fmaxf(m, __shfl_xor(m, 8));
  m = fmaxf(m, __shfl_xor(m, 16));
  m = fmaxf(m, __shfl_xor(m, 32));
  if (lane == 0) scl[wv] = (m > 0.f) ? m * (1.f / 127.f) : 1.f;
}

// ---------------- K0b: pack weights to int8 MFMA tiles ----------------
// dst[((T*8+kt)*64+lane)*16 + j] = i8(W[T*16+(lane&15)][kt*64+(lane>>4)*16+j] / scl_row)
__device__ __forceinline__ void packmatI8(u8* __restrict__ dst, const float* __restrict__ src,
                                          const float* __restrict__ sclrow,
                                          int n, int tid, int stride) {
  for (int i = tid; i < n; i += stride) {
    int j = i & 15, lane = (i >> 4) & 63, kt = (i >> 10) & 7, T = i >> 13;
    int row = T * 16 + (lane & 15);
    int col = kt * 64 + ((lane >> 4) << 4) + j;
    float s = sclrow[row];
    int q = q8(src[(size_t)row * 512 + col] / s);
    dst[i] = (u8)(q & 0xff);
  }
}

__global__ __launch_bounds__(256) void wconvert_kernel(
    const float* __restrict__ ipw, const float* __restrict__ aow,
    const float* __restrict__ ffw, const float* __restrict__ wout,
    const float* __restrict__ win, const float* __restrict__ scl,
    u8* __restrict__ win8, u8* __restrict__ wo8,
    u8* __restrict__ wf8, u8* __restrict__ wout8,
    float* __restrict__ winT)
{
  const int tid = blockIdx.x * blockDim.x + threadIdx.x;
  const int stride = gridDim.x * blockDim.x;
  packmatI8(win8,  ipw,  scl,        2*1536*E, tid, stride);
  packmatI8(wo8,   aow,  scl + 3072, 2*E*E,    tid, stride);
  packmatI8(wf8,   ffw,  scl + 4096, 2*E*E,    tid, stride);
  packmatI8(wout8, wout, scl + 5120, OUTD*E,   tid, stride);
  for (int i = tid; i < E*IND; i += stride) {
    int o = i / IND, k = i % IND;
    winT[k*E + o] = win[i];
  }
}

// ---------------- K1: X = seq @ Win^T + b_in ----------------
__global__ __launch_bounds__(512) void xproj_kernel(
    const float* __restrict__ seq, const float* __restrict__ winT,
    const float* __restrict__ b_in, float* __restrict__ X)
{
  const int b = blockIdx.x;
  const int th = threadIdx.x;
  __shared__ float sq[SS * IND];
  for (int i = th; i < SS * IND; i += 512) {
    int t = i >> 8, k = i & 255;
    sq[i] = seq[((size_t)t * BB + b) * IND + k];
  }
  __syncthreads();
  float acc[SS];
#pragma unroll
  for (int t = 0; t < SS; ++t) acc[t] = 0.f;
  for (int k = 0; k < IND; ++k) {
    float w = winT[k * E + th];
#pragma unroll
    for (int t = 0; t < SS; ++t) acc[t] += sq[t * IND + k] * w;
  }
  float bias = b_in[th];
#pragma unroll
  for (int t = 0; t < SS; ++t)
    X[((size_t)t * BB + b) * E + th] = acc[t] + bias;
}

// ---------------- K2: main recurrent encoder ----------------
__global__ __launch_bounds__(1024, 4) void encoder_kernel(
    const float* __restrict__ Xpre, const float* __restrict__ hstate,
    const u8* __restrict__ win8, const u8* __restrict__ wo8,
    const u8* __restrict__ wf8, const u8* __restrict__ wout8,
    const float* __restrict__ scl,
    const float* __restrict__ ipb, const float* __restrict__ aob,
    const float* __restrict__ l1s, const float* __restrict__ l1b,
    const float* __restrict__ l2s, const float* __restrict__ l2b,
    const float* __restrict__ ffb, const float* __restrict__ bout,
    float* __restrict__ out)
{
  const int b = blockIdx.x;
  const int th = threadIdx.x;
  const int lane = th & 63;
  const int w = th >> 6;         // wave 0..15
  const int g = lane >> 4;       // quad
  const int c = lane & 15;       // lane-in-quad
  const int fb = lane << 3;      // 8-feature chunk for LN
  const int fq = w*16 + c;       // per-lane output-feature index within a 256-block

  // per-lane byte offsets for packed-weight loads (tile w + lane + chunk)
  unsigned int vofs[8];
#pragma unroll
  for (int i = 0; i < 8; ++i)
    vofs[i] = (unsigned int)w * 8192u + (unsigned int)lane * 16u + (unsigned int)i * 1024u;

  // LDS ~95.5 KB
  __shared__ u8 h_i8[16*528];         // h int8 (x32), stride 528 (16B aligned)
  __shared__ ushort_t qk[9216];       // q[4][16][72], k[4][16][72]; dbuf alias
  __shared__ ushort_t vbuf[10240];    // vT[4][64][40] bf16 (token pads zeroed once)
  __shared__ ushort_t p_lds[2560];    // P[4][16][40] bf16 (pad cols zeroed once)
  __shared__ u8 abuf_i8[16*272];      // attn int8 (x32) -- dedicated (no qk alias)
  __shared__ ushort_t lnp[4096];      // [l][{l1s,l1b,l2s,l2b}][512] bf16
  __shared__ float x_lds[SS*E];       // X for this b, all 16 timesteps (fp32)

  ushort_t* q_lds = qk;
  ushort_t* k_lds = qk + 4608;
  ushort_t* dbuf = qk;                // [16][520] bf16

  const size_t hsb = (size_t)b * MEMD;
  const int ci0 = (int)hstate[hsb + 32768];
  const float boutr = bout[(w&7)*16 + c];
  const float mw = scl[5120 + (w&7)*16 + c] * (1.f/32.f);

  float hreg[8];
  {
#pragma unroll
    for (int j = 0; j < 8; ++j) hreg[j] = hstate[hsb + (size_t)w*E + fb + j];
    quant8_store(h_i8 + w*528 + fb, hreg);
  }
  // t=0 insert directly from global (own-wave loads, before the prologue barrier)
  if (ci0 < 16 && w == ci0) {
#pragma unroll
    for (int j = 0; j < 8; ++j) hreg[j] = Xpre[(size_t)b*E + fb + j];
    quant8_store(h_i8 + w*528 + fb, hreg);
  }
  // stage all 16 timesteps of X into LDS (coalesced; read-only afterwards)
  for (int i = th; i < SS*E; i += 1024) {
    int tt = i >> 9, e = i & 511;
    x_lds[i] = Xpre[((size_t)tt*BB + b)*E + e];
  }
  for (int i = th; i < 2560; i += 1024) p_lds[i] = 0;
  for (int i = th; i < 4096; i += 1024) {
    int h2 = i >> 10, dh = (i >> 4) & 63, t16 = i & 15;
    vbuf[h2*2560 + dh*40 + 16 + t16] = 0;
  }
  for (int i = th; i < 4096; i += 1024) {
    int l = i >> 11, arr = (i >> 9) & 3, idx = i & 511;
    float v = (arr == 0 ? l1s : arr == 1 ? l1b : arr == 2 ? l2s : l2b)[l*512 + idx];
    lnp[i] = f2bf(v);
  }
  bar_lds();

#pragma unroll 1
  for (int t = 0; t < SS; ++t) {
    const int cic = ci0 + t;
    // (x_t already inserted: t=0 in prologue, t>0 at previous WOUT tail)

#pragma unroll 1
    for (int l = 0; l < 2; ++l) {
      // per-layer biases + dequant multipliers -> registers (nothing in flight here)
      const float* bq_ = ipb + l*1536 + fq;
      const float biq0 = bq_[0],    biq1 = bq_[256];
      const float bik0 = bq_[512],  bik1 = bq_[768];
      const float biv0 = bq_[1024], biv1 = bq_[1280];
      const float aob0 = aob[l*512 + fq], aob1 = aob[l*512 + 256 + fq];
      const float ffb0 = ffb[l*512 + fq], ffb1 = ffb[l*512 + 256 + fq];
      const float* sip = scl + l*1536;
      const float mq0 = sip[fq]       * (1.f/32.f), mq1 = sip[256 + fq]  * (1.f/32.f);
      const float mk0 = sip[512 + fq] * (1.f/32.f), mk1 = sip[768 + fq]  * (1.f/32.f);
      const float mv0 = sip[1024+ fq] * (1.f/32.f), mv1 = sip[1280 + fq] * (1.f/32.f);
      const float* swo = scl + 3072 + l*512;
      const float mo0 = swo[fq] * (1.f/32.f), mo1 = swo[256 + fq] * (1.f/32.f);
      const float* swf = scl + 4096 + l*512;
      const float mf0 = swf[fq] * (1.f/32.f), mf1 = swf[256 + fq] * (1.f/32.f);

      const u8* wiL = win8 + (size_t)l*786432;
      const u8* woL = wo8 + (size_t)l*262144;
      const u8* wfL = wf8 + (size_t)l*262144;

      int4v oacc0 = {0,0,0,0}, oacc1 = oacc0;

#pragma unroll 1
      for (int pass = 0; pass < 2; ++pass) {
        const int hl = w >> 2;
        const int dhb = (w & 3) * 16;

        // ---- QKV GEMM (i8): K=512, 8 chunks x 3 streams, depth-4 pipeline ----
        {
          const u8* A8 = h_i8 + c*528 + g*16;
          const u8* uq = wiL + (size_t)pass*131072;  // block-uniform bases
          const u8* uk = uq + 262144;
          const u8* uv = uq + 524288;
          int4v aq = {0,0,0,0}, ak = aq, av = aq;
          int4v Bq[4], Bk[4], Bv[4];
          GLV(Bq[0], uq, vofs[0]); GLV(Bk[0], uk, vofs[0]); GLV(Bv[0], uv, vofs[0]);
          GLV(Bq[1], uq, vofs[1]); GLV(Bk[1], uk, vofs[1]); GLV(Bv[1], uv, vofs[1]);
          GLV(Bq[2], uq, vofs[2]); GLV(Bk[2], uk, vofs[2]); GLV(Bv[2], uv, vofs[2]);
          GLV(Bq[3], uq, vofs[3]); GLV(Bk[3], uk, vofs[3]); GLV(Bv[3], uv, vofs[3]);

#define QKV_STEP(kt2, nq, nk, nv) { \
            int4v a = *(const int4v*)(A8 + (kt2)*64); \
            WVX(Bq[(kt2)&3], nq); aq = MFMAI8(a, Bq[(kt2)&3], aq); \
            WVX(Bk[(kt2)&3], nk); ak = MFMAI8(a, Bk[(kt2)&3], ak); \
            WVX(Bv[(kt2)&3], nv); av = MFMAI8(a, Bv[(kt2)&3], av); \
            if ((kt2) < 4) { \
              GLV(Bq[(kt2)&3], uq, vofs[(kt2)+4]); \
              GLV(Bk[(kt2)&3], uk, vofs[(kt2)+4]); \
              GLV(Bv[(kt2)&3], uv, vofs[(kt2)+4]); \
            } }
          QKV_STEP(0, 11, 10, 9)
          QKV_STEP(1, 11, 10, 9)
          QKV_STEP(2, 11, 10, 9)
          QKV_STEP(3, 11, 10, 9)
          QKV_STEP(4, 11, 10, 9)
          QKV_STEP(5,  8,  7, 6)
          QKV_STEP(6,  5,  4, 3)
          QKV_STEP(7,  2,  1, 0)

          const float biq = pass ? biq1 : biq0;
          const float bik = pass ? bik1 : bik0;
          const float biv = pass ? biv1 : biv0;
          const float mq = pass ? mq1 : mq0;
          const float mk = pass ? mk1 : mk0;
          const float mv = pass ? mv1 : mv0;
#pragma unroll
          for (int r = 0; r < 4; ++r) {
            int tok = 4*g + r;
            q_lds[hl*1152 + tok*72 + dhb + c] = f2bf((float)aq[r]*mq + biq);
            k_lds[hl*1152 + tok*72 + dhb + c] = f2bf((float)ak[r]*mk + bik);
            vbuf[hl*2560 + (dhb + c)*40 + tok] = f2bf((float)av[r]*mv + biv);
          }
        }
        bar_lds();

        // ---- out-proj weights (i8): 8 loads, in flight through softmax+PV ----
        int4v O0[4], O1[4];
        {
          const u8* uo0 = woL + pass*4096;      // uniform (chunks pass*4..pass*4+3)
          const u8* uo1 = uo0 + 131072;         // tile w+16
          GLV(O0[0], uo0, vofs[0]); GLV(O1[0], uo1, vofs[0]);
          GLV(O0[1], uo0, vofs[1]); GLV(O1[1], uo1, vofs[1]);
          GLV(O0[2], uo0, vofs[2]); GLV(O1[2], uo1, vofs[2]);
          GLV(O0[3], uo0, vofs[3]); GLV(O1[3], uo1, vofs[3]);
        }

        // ---- scores + masked softmax (bf16): waves 0..3 ----
        if (w < 4) {
          f32x4 sc = {0.f,0.f,0.f,0.f};
#pragma unroll
          for (int k2 = 0; k2 < 2; ++k2) {
            short8 qa = *(const short8*)&q_lds[w*1152 + c*72 + k2*32 + g*8];
            short8 kb = *(const short8*)&k_lds[w*1152 + c*72 + k2*32 + g*8];
            sc = MFMA(qa, kb, sc, 0,0,0);
          }
          float sv[4], mx[4], ex[4], sm[4];
#pragma unroll
          for (int r = 0; r < 4; ++r) {
            int row = 4*g + r;
            bool msk = ((c > cic) || (row > cic)) && (c != 0);
            sv[r] = msk ? NEGV : sc[r]*0.125f;
            mx[r] = sv[r];
          }
#pragma unroll
          for (int r = 0; r < 4; ++r) {
            mx[r] = fmaxf(mx[r], __shfl_xor(mx[r], 1));
            mx[r] = fmaxf(mx[r], __shfl_xor(mx[r], 2));
            mx[r] = fmaxf(mx[r], __shfl_xor(mx[r], 4));
            mx[r] = fmaxf(mx[r], __shfl_xor(mx[r], 8));
          }
#pragma unroll
          for (int r = 0; r < 4; ++r) { ex[r] = __expf(sv[r] - mx[r]); sm[r] = ex[r]; }
#pragma unroll
          for (int r = 0; r < 4; ++r) {
            sm[r] += __shfl_xor(sm[r], 1);
            sm[r] += __shfl_xor(sm[r], 2);
            sm[r] += __shfl_xor(sm[r], 4);
            sm[r] += __shfl_xor(sm[r], 8);
          }
#pragma unroll
          for (int r = 0; r < 4; ++r)
            p_lds[w*640 + (4*g + r)*40 + c] = f2bf(ex[r] / sm[r]);
        }
        bar_lds();

        // ---- PV (bf16) -> abuf int8 (x32), dedicated buffer ----
        {
          const int hl2 = w >> 2, ct = w & 3;
          short8 pa = *(const short8*)&p_lds[hl2*640 + c*40 + g*8];
          short8 vb = *(const short8*)&vbuf[hl2*2560 + (ct*16 + c)*40 + g*8];
          f32x4 ov = {0.f,0.f,0.f,0.f};
          ov = MFMA(pa, vb, ov, 0,0,0);
#pragma unroll
          for (int r = 0; r < 4; ++r)
            abuf_i8[(4*g + r)*272 + hl2*64 + ct*16 + c] = (u8)(q8(ov[r]*32.f) & 0xff);
        }
        bar_lds();

        // ---- out-proj partial (i8), K=256 ----
        // no trailing barrier: QKV pass1 writes (q/k/vbuf) conflict only with
        // SM/PV pass0 reads, which are >=2 barriers upstream; abuf is dedicated.
        {
          const u8* A8o = abuf_i8 + c*272 + g*16;
#define OP_STEP(kt2, n0, n1) { \
            int4v a = *(const int4v*)(A8o + (kt2)*64); \
            WVX(O0[kt2], n0); oacc0 = MFMAI8(a, O0[kt2], oacc0); \
            WVX(O1[kt2], n1); oacc1 = MFMAI8(a, O1[kt2], oacc1); }
          OP_STEP(0, 7, 6)
          OP_STEP(1, 5, 4)
          OP_STEP(2, 3, 2)
          OP_STEP(3, 1, 0)
        }
      } // pass

      // ---- write out-proj result (dequant + attn-out bias) ----
      // dbuf overlaps q/k_lds; last readers (SM pass1) are 2 barriers upstream.
#pragma unroll
      for (int r = 0; r < 4; ++r) {
        dbuf[(4*g + r)*520 + fq]       = f2bf((float)oacc0[r]*mo0 + aob0);
        dbuf[(4*g + r)*520 + 256 + fq] = f2bf((float)oacc1[r]*mo1 + aob1);
      }
      bar_lds();

      // ---- FF weight prologue (i8, 8 loads), hides behind LN1 ----
      int4v F0[4], F1[4];
      const u8* uf0 = wfL;
      const u8* uf1 = wfL + 131072;
      GLV(F0[0], uf0, vofs[0]); GLV(F1[0], uf1, vofs[0]);
      GLV(F0[1], uf0, vofs[1]); GLV(F1[1], uf1, vofs[1]);
      GLV(F0[2], uf0, vofs[2]); GLV(F1[2], uf1, vofs[2]);
      GLV(F0[3], uf0, vofs[3]); GLV(F1[3], uf1, vofs[3]);

      // ---- residual + LN1 (params from LDS) ----
      {
        const ushort_t* lpS = lnp + l*2048;
        const ushort_t* lpB = lnp + l*2048 + 512;
        float sum = 0.f;
#pragma unroll
        for (int j = 0; j < 8; ++j) {
          hreg[j] += bf2f(dbuf[w*520 + fb + j]);
          sum += hreg[j];
        }
        sum += __shfl_xor(sum, 1); sum += __shfl_xor(sum, 2); sum += __shfl_xor(sum, 4);
        sum += __shfl_xor(sum, 8); sum += __shfl_xor(sum, 16); sum += __shfl_xor(sum, 32);
        float mu = sum * (1.0f/512.0f);
        float s2 = 0.f;
#pragma unroll
        for (int j = 0; j < 8; ++j) { float dd = hreg[j] - mu; s2 += dd*dd; }
        s2 += __shfl_xor(s2, 1); s2 += __shfl_xor(s2, 2); s2 += __shfl_xor(s2, 4);
        s2 += __shfl_xor(s2, 8); s2 += __shfl_xor(s2, 16); s2 += __shfl_xor(s2, 32);
        float rs = rsqrtf(s2 * (1.0f/512.0f) + EPSV);
#pragma unroll
        for (int j = 0; j < 8; ++j)
          hreg[j] = (hreg[j] - mu) * rs * bf2f(lpS[fb + j]) + bf2f(lpB[fb + j]);
        quant8_store(h_i8 + w*528 + fb, hreg);
      }
      bar_lds();

      // ---- FF GEMM (i8): K=512, forced pipeline ----
      {
        int4v f0 = {0,0,0,0}, f1 = f0;
        const u8* A8 = h_i8 + c*528 + g*16;
#define FF_STEP(kt2, n0, n1) { \
          int4v a = *(const int4v*)(A8 + (kt2)*64); \
          WVX(F0[(kt2)&3], n0); f0 = MFMAI8(a, F0[(kt2)&3], f0); \
          WVX(F1[(kt2)&3], n1); f1 = MFMAI8(a, F1[(kt2)&3], f1); \
          if ((kt2) < 4) { \
            GLV(F0[(kt2)&3], uf0, vofs[(kt2)+4]); \
            GLV(F1[(kt2)&3], uf1, vofs[(kt2)+4]); \
          } }
        FF_STEP(0, 7, 6)
        FF_STEP(1, 7, 6)
        FF_STEP(2, 7, 6)
        FF_STEP(3, 7, 6)
        FF_STEP(4, 7, 6)
        FF_STEP(5, 5, 4)
        FF_STEP(6, 3, 2)
        FF_STEP(7, 1, 0)
        // no barrier here: nothing reads the dbuf region during FF (LN1's
        // reads are behind the LN1-end barrier), and these writes don't
        // touch h_i8 which other waves may still be reading.
#pragma unroll
        for (int r = 0; r < 4; ++r) {
          dbuf[(4*g + r)*520 + fq]       = f2bf((float)f0[r]*mf0 + ffb0);
          dbuf[(4*g + r)*520 + 256 + fq] = f2bf((float)f1[r]*mf1 + ffb1);
        }
      }
      bar_lds();

      // ---- residual + LN2 ----
      {
        const ushort_t* lpS = lnp + l*2048 + 1024;
        const ushort_t* lpB = lnp + l*2048 + 1536;
        float sum = 0.f;
#pragma unroll
        for (int j = 0; j < 8; ++j) {
          hreg[j] += bf2f(dbuf[w*520 + fb + j]);
          sum += hreg[j];
        }
        sum += __shfl_xor(sum, 1); sum += __shfl_xor(sum, 2); sum += __shfl_xor(sum, 4);
        sum += __shfl_xor(sum, 8); sum += __shfl_xor(sum, 16); sum += __shfl_xor(sum, 32);
        float mu = sum * (1.0f/512.0f);
        float s2 = 0.f;
#pragma unroll
        for (int j = 0; j < 8; ++j) { float dd = hreg[j] - mu; s2 += dd*dd; }
        s2 += __shfl_xor(s2, 1); s2 += __shfl_xor(s2, 2); s2 += __shfl_xor(s2, 4);
        s2 += __shfl_xor(s2, 8); s2 += __shfl_xor(s2, 16); s2 += __shfl_xor(s2, 32);
        float rs = rsqrtf(s2 * (1.0f/512.0f) + EPSV);
#pragma unroll
        for (int j = 0; j < 8; ++j)
          hreg[j] = (hreg[j] - mu) * rs * bf2f(lpS[fb + j]) + bf2f(lpB[fb + j]);
        quant8_store(h_i8 + w*528 + fb, hreg);
      }
      bar_lds();
    } // layer

    // ---- output projection (i8): out_t = h[cic] @ Wout^T + b_out ----
    if (w < 8) {
      const int crow = (cic < 15) ? cic : 15;
      const u8* A8 = h_i8 + c*528 + g*16;
      int4v WB[8];
      GLV(WB[0], wout8, vofs[0]); GLV(WB[1], wout8, vofs[1]);
      GLV(WB[2], wout8, vofs[2]); GLV(WB[3], wout8, vofs[3]);
      GLV(WB[4], wout8, vofs[4]); GLV(WB[5], wout8, vofs[5]);
      GLV(WB[6], wout8, vofs[6]); GLV(WB[7], wout8, vofs[7]);
      int4v oo = {0,0,0,0};
#define WOUT_STEP(kt2, n) { \
        int4v a = *(const int4v*)(A8 + (kt2)*64); \
        WVX(WB[kt2], n); oo = MFMAI8(a, WB[kt2], oo); }
      WOUT_STEP(0, 7)
      WOUT_STEP(1, 6)
      WOUT_STEP(2, 5)
      WOUT_STEP(3, 4)
      WOUT_STEP(4, 3)
      WOUT_STEP(5, 2)
      WOUT_STEP(6, 1)
      WOUT_STEP(7, 0)
      if (g == (crow >> 2)) {
        int r = crow & 3;
        int val = (r == 0) ? oo[0] : (r == 1) ? oo[1] : (r == 2) ? oo[2] : oo[3];
        out[((size_t)t*BB + b)*OUTD + w*16 + c] = (float)val * mw + boutr;
      }
    }
    // ---- insert x_{t+1} from LDS during WOUT (racing row cic+1 is never
    // the stored row crow=cic, so its contribution to WOUT is discarded;
    // LDS-only, adds no vmem ops -> all ledgers unchanged) ----
    {
      const int nx = cic + 1;
      if (nx < 16 && w == nx) {
#pragma unroll
        for (int j = 0; j < 8; ++j) hreg[j] = x_lds[(t+1)*E + fb + j];
        quant8_store(h_i8 + w*528 + fb, hreg);
      }
    }
    bar_lds();
  } // t

  // ---- epilogue: new_h = [h_fin, pad, ci+16] ----
  const size_t OB = (size_t)SS * BB * OUTD;
#pragma unroll
  for (int j = 0; j < 8; ++j)
    out[OB + hsb + (size_t)w*E + fb + j] = hreg[j];
  for (int i = th; i < 48*512; i += 1024)
    out[OB + hsb + 8192 + i] = hstate[hsb + 8192 + i];
  if (th == 0) out[OB + hsb + 32768] = (float)(ci0 + SS);
}

// ---------------- launcher ----------------
extern "C" void kernel_launch(void* const* d_in, const int* in_sizes, int n_in,
                              void* d_out, int out_size, void* d_ws, size_t ws_size,
                              hipStream_t stream) {
  const float* seq  = (const float*)d_in[0];
  const float* hs   = (const float*)d_in[1];
  const float* Win  = (const float*)d_in[2];
  const float* b_in = (const float*)d_in[3];
  const float* Wout = (const float*)d_in[4];
  const float* bo   = (const float*)d_in[5];
  const float* ipw  = (const float*)d_in[6];
  const float* ipb  = (const float*)d_in[7];
  const float* aow  = (const float*)d_in[8];
  const float* aob  = (const float*)d_in[9];
  const float* l1s  = (const float*)d_in[10];
  const float* l1b  = (const float*)d_in[11];
  const float* l2s  = (const float*)d_in[12];
  const float* l2b  = (const float*)d_in[13];
  const float* ffw  = (const float*)d_in[14];
  const float* ffb  = (const float*)d_in[15];

  char* ws = (char*)d_ws;
  u8*    win8  = (u8*)   (ws + 0);          // 1,572,864 B
  u8*    wo8   = (u8*)   (ws + 1572864);    //   524,288 B
  u8*    wf8   = (u8*)   (ws + 2097152);    //   524,288 B
  u8*    wout8 = (u8*)   (ws + 2621440);    //    65,536 B
  float* scl   = (float*)(ws + 2686976);    //    20,992 B (5248 f32)
  float* winT  = (float*)(ws + 2707968);    //   524,288 B
  float* X     = (float*)(ws + 3232256);    // 4,194,304 B

  wscale_kernel<<<1312, 256, 0, stream>>>(ipw, aow, ffw, Wout, scl);
  wconvert_kernel<<<512, 256, 0, stream>>>(ipw, aow, ffw, Wout, Win, scl,
                                           win8, wo8, wf8, wout8, winT);
  xproj_kernel<<<BB, 512, 0, stream>>>(seq, winT, b_in, X);
  encoder_kernel<<<BB, 1024, 0, stream>>>(X, hs, win8, wo8, wf8, wout8, scl,
                                          ipb, aob, l1s, l1b, l2s, l2b, ffb, bo,
                                          (float*)d_out);
}

// Round 12
// 777.340 us; speedup vs baseline: 1.0921x; 1.0306x over previous
//
#include <hip/hip_runtime.h>

typedef __attribute__((ext_vector_type(8))) short short8;
typedef __attribute__((ext_vector_type(4))) float f32x4;
typedef __attribute__((ext_vector_type(4))) int int4v;
typedef unsigned short ushort_t;
typedef unsigned char u8;

#define E 512
#define SS 16
#define BB 128
#define IND 256
#define OUTD 128
#define MEMD 32769
#define NEGV -1000000000.0f
#define EPSV 1e-5f

#define MFMA  __builtin_amdgcn_mfma_f32_16x16x32_bf16
#define MFMAI8(a, b, c) __builtin_amdgcn_mfma_i32_16x16x64_i8((a), (b), (c), 0, 0, 0)

// forced-issue 16B load, saddr form: base block-uniform (SGPR pair),
// thread-dependent terms in the per-lane VGPR offset.
#define GLV(dst, base, off) \
  asm volatile("global_load_dwordx4 %0, %1, %2" : "=v"(dst) : "v"(off), "s"(base))
// wait tied to consumed register
#define WVX_(x, n) asm volatile("s_waitcnt vmcnt(" #n ")" : "+v"(x))
#define WVX(x, n) WVX_(x, n)

// LDS-only barrier: does not drain vmcnt
__device__ __forceinline__ void bar_lds() {
  asm volatile("s_waitcnt lgkmcnt(0)\ns_barrier" ::: "memory");
}

__device__ __forceinline__ unsigned short f2bf(float f) {
  union { float f; unsigned int u; } v; v.f = f;
  unsigned int u = v.u;
  unsigned int r = u + 0x7fffu + ((u >> 16) & 1u);
  return (unsigned short)(r >> 16);
}
__device__ __forceinline__ float bf2f(unsigned short h) {
  union { unsigned int u; float f; } v; v.u = ((unsigned int)h) << 16;
  return v.f;
}
__device__ __forceinline__ int q8(float x) {  // round-to-nearest int8 with clamp
  return __float2int_rn(fminf(fmaxf(x, -127.f), 127.f));
}
// quantize 8 fp32 (scale 32) -> 8 int8 packed into two dwords at dst
__device__ __forceinline__ void quant8_store(u8* dst, const float* h) {
  int q[8];
#pragma unroll
  for (int j = 0; j < 8; ++j) q[j] = q8(h[j] * 32.f);
  unsigned int p0 = (q[0]&255) | ((q[1]&255)<<8) | ((q[2]&255)<<16) | ((q[3]&255)<<24);
  unsigned int p1 = (q[4]&255) | ((q[5]&255)<<8) | ((q[6]&255)<<16) | ((q[7]&255)<<24);
  *(unsigned int*)(dst)     = p0;
  *(unsigned int*)(dst + 4) = p1;
}

// ---------------- K0a: per-row weight scales (wave-per-row, coalesced) ----------------
// rows: [0,3072)=ipw(2x1536), [3072,4096)=aow(2x512), [4096,5120)=ffw(2x512), [5120,5248)=wout(128)
__global__ __launch_bounds__(256) void wscale_kernel(
    const float* __restrict__ ipw, const float* __restrict__ aow,
    const float* __restrict__ ffw, const float* __restrict__ wout,
    float* __restrict__ scl)
{
  int wv = blockIdx.x * 4 + (threadIdx.x >> 6);   // grid 1312*4 = 5248 rows exactly
  int lane = threadIdx.x & 63;
  const float* row;
  if (wv < 3072)      row = ipw  + (size_t)wv * 512;
  else if (wv < 4096) row = aow  + (size_t)(wv - 3072) * 512;
  else if (wv < 5120) row = ffw  + (size_t)(wv - 4096) * 512;
  else                row = wout + (size_t)(wv - 5120) * 512;
  float m = 0.f;
#pragma unroll
  for (int k = 0; k < 8; ++k) m = fmaxf(m, fabsf(row[lane + 64*k]));
  m = fmaxf(m, __shfl_xor(m, 1));
  m = fmaxf(m, __shfl_xor(m, 2));
  m = fmaxf(m, __shfl_xor(m, 4));
  m = fmaxf(m, __shfl_xor(m, 8));
  m = fmaxf(m, __shfl_xor(m, 16));
  m = fmaxf(m, __shfl_xor(m, 32));
  if (lane == 0) scl[wv] = (m > 0.f) ? m * (1.f / 127.f) : 1.f;
}

// ---------------- K0b: pack weights to int8 MFMA tiles ----------------
// dst[((T*8+kt)*64+lane)*16 + j] = i8(W[T*16+(lane&15)][kt*64+(lane>>4)*16+j] / scl_row)
__device__ __forceinline__ void packmatI8(u8* __restrict__ dst, const float* __restrict__ src,
                                          const float* __restrict__ sclrow,
                                          int n, int tid, int stride) {
  for (int i = tid; i < n; i += stride) {
    int j = i & 15, lane = (i >> 4) & 63, kt = (i >> 10) & 7, T = i >> 13;
    int row = T * 16 + (lane & 15);
    int col = kt * 64 + ((lane >> 4) << 4) + j;
    float s = sclrow[row];
    int q = q8(src[(size_t)row * 512 + col] / s);
    dst[i] = (u8)(q & 0xff);
  }
}

__global__ __launch_bounds__(256) void wconvert_kernel(
    const float* __restrict__ ipw, const float* __restrict__ aow,
    const float* __restrict__ ffw, const float* __restrict__ wout,
    const float* __restrict__ win, const float* __restrict__ scl,
    u8* __restrict__ win8, u8* __restrict__ wo8,
    u8* __restrict__ wf8, u8* __restrict__ wout8,
    float* __restrict__ winT)
{
  const int tid = blockIdx.x * blockDim.x + threadIdx.x;
  const int stride = gridDim.x * blockDim.x;
  packmatI8(win8,  ipw,  scl,        2*1536*E, tid, stride);
  packmatI8(wo8,   aow,  scl + 3072, 2*E*E,    tid, stride);
  packmatI8(wf8,   ffw,  scl + 4096, 2*E*E,    tid, stride);
  packmatI8(wout8, wout, scl + 5120, OUTD*E,   tid, stride);
  for (int i = tid; i < E*IND; i += stride) {
    int o = i / IND, k = i % IND;
    winT[k*E + o] = win[i];
  }
}

// ---------------- K1: X = seq @ Win^T + b_in ----------------
__global__ __launch_bounds__(512) void xproj_kernel(
    const float* __restrict__ seq, const float* __restrict__ winT,
    const float* __restrict__ b_in, float* __restrict__ X)
{
  const int b = blockIdx.x;
  const int th = threadIdx.x;
  __shared__ float sq[SS * IND];
  for (int i = th; i < SS * IND; i += 512) {
    int t = i >> 8, k = i & 255;
    sq[i] = seq[((size_t)t * BB + b) * IND + k];
  }
  __syncthreads();
  float acc[SS];
#pragma unroll
  for (int t = 0; t < SS; ++t) acc[t] = 0.f;
  for (int k = 0; k < IND; ++k) {
    float w = winT[k * E + th];
#pragma unroll
    for (int t = 0; t < SS; ++t) acc[t] += sq[t * IND + k] * w;
  }
  float bias = b_in[th];
#pragma unroll
  for (int t = 0; t < SS; ++t)
    X[((size_t)t * BB + b) * E + th] = acc[t] + bias;
}

// ---------------- K2: main recurrent encoder ----------------
__global__ __launch_bounds__(1024, 4) void encoder_kernel(
    const float* __restrict__ Xpre, const float* __restrict__ hstate,
    const u8* __restrict__ win8, const u8* __restrict__ wo8,
    const u8* __restrict__ wf8, const u8* __restrict__ wout8,
    const float* __restrict__ scl,
    const float* __restrict__ ipb, const float* __restrict__ aob,
    const float* __restrict__ l1s, const float* __restrict__ l1b,
    const float* __restrict__ l2s, const float* __restrict__ l2b,
    const float* __restrict__ ffb, const float* __restrict__ bout,
    float* __restrict__ out)
{
  const int b = blockIdx.x;
  const int th = threadIdx.x;
  const int lane = th & 63;
  const int w = th >> 6;         // wave 0..15
  const int g = lane >> 4;       // quad
  const int c = lane & 15;       // lane-in-quad
  const int fb = lane << 3;      // 8-feature chunk for LN
  const int fq = w*16 + c;       // per-lane output-feature index within a 256-block

  // per-lane byte offsets for packed-weight loads (tile w + lane + chunk)
  unsigned int vofs[8];
#pragma unroll
  for (int i = 0; i < 8; ++i)
    vofs[i] = (unsigned int)w * 8192u + (unsigned int)lane * 16u + (unsigned int)i * 1024u;

  // LDS ~65 KB
  __shared__ u8 h_i8[16*528];         // h int8 (x32), stride 528 (16B aligned)
  __shared__ ushort_t qk[9216];       // q[4][16][72], k[4][16][72]; dbuf alias
  __shared__ ushort_t vbuf[10240];    // vT[4][64][40] bf16 (token pads zeroed once)
  __shared__ ushort_t p_lds[2560];    // P[4][16][40] bf16 (pad cols zeroed once)
  __shared__ u8 abuf_i8[16*272];      // attn int8 (x32) -- dedicated (no qk alias)
  __shared__ ushort_t lnp[4096];      // [l][{l1s,l1b,l2s,l2b}][512] bf16

  ushort_t* q_lds = qk;
  ushort_t* k_lds = qk + 4608;
  ushort_t* dbuf = qk;                // [16][520] bf16

  const size_t hsb = (size_t)b * MEMD;
  const int ci0 = (int)hstate[hsb + 32768];
  const float boutr = bout[(w&7)*16 + c];
  const float mw = scl[5120 + (w&7)*16 + c] * (1.f/32.f);

  float hreg[8];
  {
#pragma unroll
    for (int j = 0; j < 8; ++j) hreg[j] = hstate[hsb + (size_t)w*E + fb + j];
    quant8_store(h_i8 + w*528 + fb, hreg);
  }
  for (int i = th; i < 2560; i += 1024) p_lds[i] = 0;
  for (int i = th; i < 4096; i += 1024) {
    int h2 = i >> 10, dh = (i >> 4) & 63, t16 = i & 15;
    vbuf[h2*2560 + dh*40 + 16 + t16] = 0;
  }
  for (int i = th; i < 4096; i += 1024) {
    int l = i >> 11, arr = (i >> 9) & 3, idx = i & 511;
    float v = (arr == 0 ? l1s : arr == 1 ? l1b : arr == 2 ? l2s : l2b)[l*512 + idx];
    lnp[i] = f2bf(v);
  }
  bar_lds();

#pragma unroll 1
  for (int t = 0; t < SS; ++t) {
    const int cic = ci0 + t;
    if (cic < 16 && w == cic) {
#pragma unroll
      for (int j = 0; j < 8; ++j) hreg[j] = Xpre[((size_t)t*BB + b)*E + fb + j];
      quant8_store(h_i8 + w*528 + fb, hreg);
    }
    bar_lds();

#pragma unroll 1
    for (int l = 0; l < 2; ++l) {
      // per-layer biases + dequant multipliers -> registers (nothing in flight here)
      const float* bq_ = ipb + l*1536 + fq;
      const float biq0 = bq_[0],    biq1 = bq_[256];
      const float bik0 = bq_[512],  bik1 = bq_[768];
      const float biv0 = bq_[1024], biv1 = bq_[1280];
      const float aob0 = aob[l*512 + fq], aob1 = aob[l*512 + 256 + fq];
      const float ffb0 = ffb[l*512 + fq], ffb1 = ffb[l*512 + 256 + fq];
      const float* sip = scl + l*1536;
      const float mq0 = sip[fq]       * (1.f/32.f), mq1 = sip[256 + fq]  * (1.f/32.f);
      const float mk0 = sip[512 + fq] * (1.f/32.f), mk1 = sip[768 + fq]  * (1.f/32.f);
      const float mv0 = sip[1024+ fq] * (1.f/32.f), mv1 = sip[1280 + fq] * (1.f/32.f);
      const float* swo = scl + 3072 + l*512;
      const float mo0 = swo[fq] * (1.f/32.f), mo1 = swo[256 + fq] * (1.f/32.f);
      const float* swf = scl + 4096 + l*512;
      const float mf0 = swf[fq] * (1.f/32.f), mf1 = swf[256 + fq] * (1.f/32.f);

      const u8* wiL = win8 + (size_t)l*786432;
      const u8* woL = wo8 + (size_t)l*262144;
      const u8* wfL = wf8 + (size_t)l*262144;

      int4v oacc0 = {0,0,0,0}, oacc1 = oacc0;

#pragma unroll 1
      for (int pass = 0; pass < 2; ++pass) {
        const int hl = w >> 2;
        const int dhb = (w & 3) * 16;

        // ---- QKV GEMM (i8): K=512, 8 chunks x 3 streams, depth-4 pipeline ----
        {
          const u8* A8 = h_i8 + c*528 + g*16;
          const u8* uq = wiL + (size_t)pass*131072;  // block-uniform bases
          const u8* uk = uq + 262144;
          const u8* uv = uq + 524288;
          int4v aq = {0,0,0,0}, ak = aq, av = aq;
          int4v Bq[4], Bk[4], Bv[4];
          GLV(Bq[0], uq, vofs[0]); GLV(Bk[0], uk, vofs[0]); GLV(Bv[0], uv, vofs[0]);
          GLV(Bq[1], uq, vofs[1]); GLV(Bk[1], uk, vofs[1]); GLV(Bv[1], uv, vofs[1]);
          GLV(Bq[2], uq, vofs[2]); GLV(Bk[2], uk, vofs[2]); GLV(Bv[2], uv, vofs[2]);
          GLV(Bq[3], uq, vofs[3]); GLV(Bk[3], uk, vofs[3]); GLV(Bv[3], uv, vofs[3]);

#define QKV_STEP(kt2, nq, nk, nv) { \
            int4v a = *(const int4v*)(A8 + (kt2)*64); \
            WVX(Bq[(kt2)&3], nq); aq = MFMAI8(a, Bq[(kt2)&3], aq); \
            WVX(Bk[(kt2)&3], nk); ak = MFMAI8(a, Bk[(kt2)&3], ak); \
            WVX(Bv[(kt2)&3], nv); av = MFMAI8(a, Bv[(kt2)&3], av); \
            if ((kt2) < 4) { \
              GLV(Bq[(kt2)&3], uq, vofs[(kt2)+4]); \
              GLV(Bk[(kt2)&3], uk, vofs[(kt2)+4]); \
              GLV(Bv[(kt2)&3], uv, vofs[(kt2)+4]); \
            } }
          QKV_STEP(0, 11, 10, 9)
          QKV_STEP(1, 11, 10, 9)
          QKV_STEP(2, 11, 10, 9)
          QKV_STEP(3, 11, 10, 9)
          QKV_STEP(4, 11, 10, 9)
          QKV_STEP(5,  8,  7, 6)
          QKV_STEP(6,  5,  4, 3)
          QKV_STEP(7,  2,  1, 0)

          const float biq = pass ? biq1 : biq0;
          const float bik = pass ? bik1 : bik0;
          const float biv = pass ? biv1 : biv0;
          const float mq = pass ? mq1 : mq0;
          const float mk = pass ? mk1 : mk0;
          const float mv = pass ? mv1 : mv0;
#pragma unroll
          for (int r = 0; r < 4; ++r) {
            int tok = 4*g + r;
            q_lds[hl*1152 + tok*72 + dhb + c] = f2bf((float)aq[r]*mq + biq);
            k_lds[hl*1152 + tok*72 + dhb + c] = f2bf((float)ak[r]*mk + bik);
            vbuf[hl*2560 + (dhb + c)*40 + tok] = f2bf((float)av[r]*mv + biv);
          }
        }
        bar_lds();

        // ---- out-proj weights (i8): 8 loads, in flight through softmax+PV ----
        int4v O0[4], O1[4];
        {
          const u8* uo0 = woL + pass*4096;      // uniform (chunks pass*4..pass*4+3)
          const u8* uo1 = uo0 + 131072;         // tile w+16
          GLV(O0[0], uo0, vofs[0]); GLV(O1[0], uo1, vofs[0]);
          GLV(O0[1], uo0, vofs[1]); GLV(O1[1], uo1, vofs[1]);
          GLV(O0[2], uo0, vofs[2]); GLV(O1[2], uo1, vofs[2]);
          GLV(O0[3], uo0, vofs[3]); GLV(O1[3], uo1, vofs[3]);
        }

        // ---- scores + masked softmax (bf16): waves 0..3 ----
        if (w < 4) {
          f32x4 sc = {0.f,0.f,0.f,0.f};
#pragma unroll
          for (int k2 = 0; k2 < 2; ++k2) {
            short8 qa = *(const short8*)&q_lds[w*1152 + c*72 + k2*32 + g*8];
            short8 kb = *(const short8*)&k_lds[w*1152 + c*72 + k2*32 + g*8];
            sc = MFMA(qa, kb, sc, 0,0,0);
          }
          float sv[4], mx[4], ex[4], sm[4];
#pragma unroll
          for (int r = 0; r < 4; ++r) {
            int row = 4*g + r;
            bool msk = ((c > cic) || (row > cic)) && (c != 0);
            sv[r] = msk ? NEGV : sc[r]*0.125f;
            mx[r] = sv[r];
          }
#pragma unroll
          for (int r = 0; r < 4; ++r) {
            mx[r] = fmaxf(mx[r], __shfl_xor(mx[r], 1));
            mx[r] = fmaxf(mx[r], __shfl_xor(mx[r], 2));
            mx[r] = fmaxf(mx[r], __shfl_xor(mx[r], 4));
            mx[r] = fmaxf(mx[r], __shfl_xor(mx[r], 8));
          }
#pragma unroll
          for (int r = 0; r < 4; ++r) { ex[r] = __expf(sv[r] - mx[r]); sm[r] = ex[r]; }
#pragma unroll
          for (int r = 0; r < 4; ++r) {
            sm[r] += __shfl_xor(sm[r], 1);
            sm[r] += __shfl_xor(sm[r], 2);
            sm[r] += __shfl_xor(sm[r], 4);
            sm[r] += __shfl_xor(sm[r], 8);
          }
#pragma unroll
          for (int r = 0; r < 4; ++r)
            p_lds[w*640 + (4*g + r)*40 + c] = f2bf(ex[r] / sm[r]);
        }
        bar_lds();

        // ---- PV (bf16) -> abuf int8 (x32), dedicated buffer ----
        {
          const int hl2 = w >> 2, ct = w & 3;
          short8 pa = *(const short8*)&p_lds[hl2*640 + c*40 + g*8];
          short8 vb = *(const short8*)&vbuf[hl2*2560 + (ct*16 + c)*40 + g*8];
          f32x4 ov = {0.f,0.f,0.f,0.f};
          ov = MFMA(pa, vb, ov, 0,0,0);
#pragma unroll
          for (int r = 0; r < 4; ++r)
            abuf_i8[(4*g + r)*272 + hl2*64 + ct*16 + c] = (u8)(q8(ov[r]*32.f) & 0xff);
        }
        bar_lds();

        // ---- out-proj partial (i8), K=256 ----
        // no trailing barrier: QKV pass1 writes (q/k/vbuf) conflict only with
        // SM/PV pass0 reads, which are >=2 barriers upstream; abuf is dedicated.
        {
          const u8* A8o = abuf_i8 + c*272 + g*16;
#define OP_STEP(kt2, n0, n1) { \
            int4v a = *(const int4v*)(A8o + (kt2)*64); \
            WVX(O0[kt2], n0); oacc0 = MFMAI8(a, O0[kt2], oacc0); \
            WVX(O1[kt2], n1); oacc1 = MFMAI8(a, O1[kt2], oacc1); }
          OP_STEP(0, 7, 6)
          OP_STEP(1, 5, 4)
          OP_STEP(2, 3, 2)
          OP_STEP(3, 1, 0)
        }
      } // pass

      // ---- write out-proj result (dequant + attn-out bias) ----
      // dbuf overlaps q/k_lds; last readers (SM pass1) are 2 barriers upstream.
#pragma unroll
      for (int r = 0; r < 4; ++r) {
        dbuf[(4*g + r)*520 + fq]       = f2bf((float)oacc0[r]*mo0 + aob0);
        dbuf[(4*g + r)*520 + 256 + fq] = f2bf((float)oacc1[r]*mo1 + aob1);
      }
      bar_lds();

      // ---- FF weight prologue (i8, 8 loads), hides behind LN1 ----
      int4v F0[4], F1[4];
      const u8* uf0 = wfL;
      const u8* uf1 = wfL + 131072;
      GLV(F0[0], uf0, vofs[0]); GLV(F1[0], uf1, vofs[0]);
      GLV(F0[1], uf0, vofs[1]); GLV(F1[1], uf1, vofs[1]);
      GLV(F0[2], uf0, vofs[2]); GLV(F1[2], uf1, vofs[2]);
      GLV(F0[3], uf0, vofs[3]); GLV(F1[3], uf1, vofs[3]);

      // ---- residual + LN1 (params from LDS) ----
      {
        const ushort_t* lpS = lnp + l*2048;
        const ushort_t* lpB = lnp + l*2048 + 512;
        float sum = 0.f;
#pragma unroll
        for (int j = 0; j < 8; ++j) {
          hreg[j] += bf2f(dbuf[w*520 + fb + j]);
          sum += hreg[j];
        }
        sum += __shfl_xor(sum, 1); sum += __shfl_xor(sum, 2); sum += __shfl_xor(sum, 4);
        sum += __shfl_xor(sum, 8); sum += __shfl_xor(sum, 16); sum += __shfl_xor(sum, 32);
        float mu = sum * (1.0f/512.0f);
        float s2 = 0.f;
#pragma unroll
        for (int j = 0; j < 8; ++j) { float dd = hreg[j] - mu; s2 += dd*dd; }
        s2 += __shfl_xor(s2, 1); s2 += __shfl_xor(s2, 2); s2 += __shfl_xor(s2, 4);
        s2 += __shfl_xor(s2, 8); s2 += __shfl_xor(s2, 16); s2 += __shfl_xor(s2, 32);
        float rs = rsqrtf(s2 * (1.0f/512.0f) + EPSV);
#pragma unroll
        for (int j = 0; j < 8; ++j)
          hreg[j] = (hreg[j] - mu) * rs * bf2f(lpS[fb + j]) + bf2f(lpB[fb + j]);
        quant8_store(h_i8 + w*528 + fb, hreg);
      }
      bar_lds();

      // ---- FF GEMM (i8): K=512, forced pipeline ----
      {
        int4v f0 = {0,0,0,0}, f1 = f0;
        const u8* A8 = h_i8 + c*528 + g*16;
#define FF_STEP(kt2, n0, n1) { \
          int4v a = *(const int4v*)(A8 + (kt2)*64); \
          WVX(F0[(kt2)&3], n0); f0 = MFMAI8(a, F0[(kt2)&3], f0); \
          WVX(F1[(kt2)&3], n1); f1 = MFMAI8(a, F1[(kt2)&3], f1); \
          if ((kt2) < 4) { \
            GLV(F0[(kt2)&3], uf0, vofs[(kt2)+4]); \
            GLV(F1[(kt2)&3], uf1, vofs[(kt2)+4]); \
          } }
        FF_STEP(0, 7, 6)
        FF_STEP(1, 7, 6)
        FF_STEP(2, 7, 6)
        FF_STEP(3, 7, 6)
        FF_STEP(4, 7, 6)
        FF_STEP(5, 5, 4)
        FF_STEP(6, 3, 2)
        FF_STEP(7, 1, 0)
        // no barrier here: nothing reads the dbuf region during FF (LN1's
        // reads are behind the LN1-end barrier), and these writes don't
        // touch h_i8 which other waves may still be reading.
#pragma unroll
        for (int r = 0; r < 4; ++r) {
          dbuf[(4*g + r)*520 + fq]       = f2bf((float)f0[r]*mf0 + ffb0);
          dbuf[(4*g + r)*520 + 256 + fq] = f2bf((float)f1[r]*mf1 + ffb1);
        }
      }
      bar_lds();

      // ---- residual + LN2 ----
      {
        const ushort_t* lpS = lnp + l*2048 + 1024;
        const ushort_t* lpB = lnp + l*2048 + 1536;
        float sum = 0.f;
#pragma unroll
        for (int j = 0; j < 8; ++j) {
          hreg[j] += bf2f(dbuf[w*520 + fb + j]);
          sum += hreg[j];
        }
        sum += __shfl_xor(sum, 1); sum += __shfl_xor(sum, 2); sum += __shfl_xor(sum, 4);
        sum += __shfl_xor(sum, 8); sum += __shfl_xor(sum, 16); sum += __shfl_xor(sum, 32);
        float mu = sum * (1.0f/512.0f);
        float s2 = 0.f;
#pragma unroll
        for (int j = 0; j < 8; ++j) { float dd = hreg[j] - mu; s2 += dd*dd; }
        s2 += __shfl_xor(s2, 1); s2 += __shfl_xor(s2, 2); s2 += __shfl_xor(s2, 4);
        s2 += __shfl_xor(s2, 8); s2 += __shfl_xor(s2, 16); s2 += __shfl_xor(s2, 32);
        float rs = rsqrtf(s2 * (1.0f/512.0f) + EPSV);
#pragma unroll
        for (int j = 0; j < 8; ++j)
          hreg[j] = (hreg[j] - mu) * rs * bf2f(lpS[fb + j]) + bf2f(lpB[fb + j]);
        quant8_store(h_i8 + w*528 + fb, hreg);
      }
      bar_lds();
    } // layer

    // ---- output projection (i8): out_t = h[cic] @ Wout^T + b_out ----
    if (w < 8) {
      const int crow = (cic < 15) ? cic : 15;
      const u8* A8 = h_i8 + c*528 + g*16;
      int4v WB[8];
      GLV(WB[0], wout8, vofs[0]); GLV(WB[1], wout8, vofs[1]);
      GLV(WB[2], wout8, vofs[2]); GLV(WB[3], wout8, vofs[3]);
      GLV(WB[4], wout8, vofs[4]); GLV(WB[5], wout8, vofs[5]);
      GLV(WB[6], wout8, vofs[6]); GLV(WB[7], wout8, vofs[7]);
      int4v oo = {0,0,0,0};
#define WOUT_STEP(kt2, n) { \
        int4v a = *(const int4v*)(A8 + (kt2)*64); \
        WVX(WB[kt2], n); oo = MFMAI8(a, WB[kt2], oo); }
      WOUT_STEP(0, 7)
      WOUT_STEP(1, 6)
      WOUT_STEP(2, 5)
      WOUT_STEP(3, 4)
      WOUT_STEP(4, 3)
      WOUT_STEP(5, 2)
      WOUT_STEP(6, 1)
      WOUT_STEP(7, 0)
      if (g == (crow >> 2)) {
        int r = crow & 3;
        int val = (r == 0) ? oo[0] : (r == 1) ? oo[1] : (r == 2) ? oo[2] : oo[3];
        out[((size_t)t*BB + b)*OUTD + w*16 + c] = (float)val * mw + boutr;
      }
    }
    bar_lds();
  } // t

  // ---- epilogue: new_h = [h_fin, pad, ci+16] ----
  const size_t OB = (size_t)SS * BB * OUTD;
#pragma unroll
  for (int j = 0; j < 8; ++j)
    out[OB + hsb + (size_t)w*E + fb + j] = hreg[j];
  for (int i = th; i < 48*512; i += 1024)
    out[OB + hsb + 8192 + i] = hstate[hsb + 8192 + i];
  if (th == 0) out[OB + hsb + 32768] = (float)(ci0 + SS);
}

// ---------------- launcher ----------------
extern "C" void kernel_launch(void* const* d_in, const int* in_sizes, int n_in,
                              void* d_out, int out_size, void* d_ws, size_t ws_size,
                              hipStream_t stream) {
  const float* seq  = (const float*)d_in[0];
  const float* hs   = (const float*)d_in[1];
  const float* Win  = (const float*)d_in[2];
  const float* b_in = (const float*)d_in[3];
  const float* Wout = (const float*)d_in[4];
  const float* bo   = (const float*)d_in[5];
  const float* ipw  = (const float*)d_in[6];
  const float* ipb  = (const float*)d_in[7];
  const float* aow  = (const float*)d_in[8];
  const float* aob  = (const float*)d_in[9];
  const float* l1s  = (const float*)d_in[10];
  const float* l1b  = (const float*)d_in[11];
  const float* l2s  = (const float*)d_in[12];
  const float* l2b  = (const float*)d_in[13];
  const float* ffw  = (const float*)d_in[14];
  const float* ffb  = (const float*)d_in[15];

  char* ws = (char*)d_ws;
  u8*    win8  = (u8*)   (ws + 0);          // 1,572,864 B
  u8*    wo8   = (u8*)   (ws + 1572864);    //   524,288 B
  u8*    wf8   = (u8*)   (ws + 2097152);    //   524,288 B
  u8*    wout8 = (u8*)   (ws + 2621440);    //    65,536 B
  float* scl   = (float*)(ws + 2686976);    //    20,992 B (5248 f32)
  float* winT  = (float*)(ws + 2707968);    //   524,288 B
  float* X     = (float*)(ws + 3232256);    // 4,194,304 B

  wscale_kernel<<<1312, 256, 0, stream>>>(ipw, aow, ffw, Wout, scl);
  wconvert_kernel<<<512, 256, 0, stream>>>(ipw, aow, ffw, Wout, Win, scl,
                                           win8, wo8, wf8, wout8, winT);
  xproj_kernel<<<BB, 512, 0, stream>>>(seq, winT, b_in, X);
  encoder_kernel<<<BB, 1024, 0, stream>>>(X, hs, win8, wo8, wf8, wout8, scl,
                                          ipb, aob, l1s, l1b, l2s, l2b, ffb, bo,
                                          (float*)d_out);
}